// Round 1
// baseline (354.885 us; speedup 1.0000x reference)
//
#include <hip/hip_runtime.h>
#include <hip/hip_bf16.h>

#define B_   16
#define T_   243
#define J_   17
#define E_   256
#define D_   257
#define BJ_  (B_ * J_)      // 272
#define M_   (BJ_ * T_)     // 66096
#define MPAD_ 66176         // 517 * 128

typedef __bf16 bf16x8 __attribute__((ext_vector_type(8)));
typedef float  f32x4  __attribute__((ext_vector_type(4)));

static __device__ __forceinline__ float bf2f(unsigned short u) {
  unsigned int v = ((unsigned int)u) << 16;
  return __builtin_bit_cast(float, v);
}
static __device__ __forceinline__ unsigned short f2bf(float f) {
  __hip_bfloat16 h = __float2bfloat16(f);
  return __builtin_bit_cast(unsigned short, h);
}
static __device__ __forceinline__ float wave_sum(float v) {
  v += __shfl_xor(v, 1);
  v += __shfl_xor(v, 2);
  v += __shfl_xor(v, 4);
  v += __shfl_xor(v, 8);
  v += __shfl_xor(v, 16);
  v += __shfl_xor(v, 32);
  return v;
}
static __device__ __forceinline__ void gload_lds16(const void* g, void* l) {
  __builtin_amdgcn_global_load_lds(
      (const __attribute__((address_space(1))) void*)g,
      (__attribute__((address_space(3))) void*)l, 16, 0, 0);
}

// ---------------------------------------------------------------------------
// K0: fuse Wq/Wk/Wv (fp32, [256][256] row-major, n-major) -> bf16 [768][256]
// ---------------------------------------------------------------------------
__global__ void fuse_w_kernel(const float* __restrict__ Wq,
                              const float* __restrict__ Wk,
                              const float* __restrict__ Wv,
                              __hip_bfloat16* __restrict__ wf) {
  int idx = blockIdx.x * 256 + threadIdx.x;  // 0 .. 196607
  float v = (idx < 65536) ? Wq[idx]
          : (idx < 131072) ? Wk[idx - 65536]
                           : Wv[idx - 131072];
  ((unsigned short*)wf)[idx] = f2bf(v);
}

// ---------------------------------------------------------------------------
// K1: spatial = acosh(max(x_t,1+1e-7)) / clip(||x_s||,1e-7) * x_s  -> bf16
// one wave per (bj, t) row; output row-major [M_][256], m = bj*T + t
// ---------------------------------------------------------------------------
__global__ __launch_bounds__(256) void spatial_kernel(
    const float* __restrict__ x, unsigned short* __restrict__ sp) {
  int wid  = threadIdx.x >> 6;
  int lane = threadIdx.x & 63;
  int t = blockIdx.x * 4 + wid;
  if (t >= T_) return;
  int bj = blockIdx.y;
  int b = bj / J_, j = bj % J_;
  const float* row = x + ((size_t)(b * T_ + t) * J_ + j) * D_;

  float xs[4];
  float ss = 0.f;
#pragma unroll
  for (int i = 0; i < 4; ++i) {
    xs[i] = row[1 + lane * 4 + i];
    ss += xs[i] * xs[i];
  }
  ss = wave_sum(ss);
  float xn = fmaxf(sqrtf(ss), 1e-7f);
  float xt = row[0];
  float alpha = acoshf(fmaxf(xt, 1.f + 1e-7f)) / xn;

  size_t m = (size_t)bj * T_ + t;
  ushort4 o;
  o.x = f2bf(xs[0] * alpha);
  o.y = f2bf(xs[1] * alpha);
  o.z = f2bf(xs[2] * alpha);
  o.w = f2bf(xs[3] * alpha);
  *(ushort4*)(sp + m * 256 + lane * 4) = o;
}

// ---------------------------------------------------------------------------
// K2: fused QKV GEMM: C[m][n] = sum_k A[m][k] * Wf[n][k] + bias[n]
// A: bf16 [MPAD_][256] (rows >= M_ clamped on load), Wf: bf16 [768][256]
// C: bf16 [MPAD_][768].  128x128 tile, BK=64, 4 waves (2x2 of 64x64).
// global_load_lds w/ pre-swizzled source; ds_read_b128 w/ XOR swizzle.
// ---------------------------------------------------------------------------
__global__ __launch_bounds__(256) void qkv_gemm_kernel(
    const unsigned short* __restrict__ A, const unsigned short* __restrict__ Wf,
    const float* __restrict__ bq, const float* __restrict__ bk,
    const float* __restrict__ bv, unsigned short* __restrict__ C) {
  __shared__ unsigned short lA[128 * 64];
  __shared__ unsigned short lB[128 * 64];
  int tid = threadIdx.x;
  int w = tid >> 6, lane = tid & 63;
  int wr = w >> 1, wc = w & 1;
  int m0 = blockIdx.x * 128, n0 = blockIdx.y * 128;

  // staging geometry: per issue, wave w covers rows [i*32+w*8, +8), lane l ->
  // row += l/8, 16B slot (l%8) XOR'd against row&7 (inverse of read swizzle)
  int rowInWave = lane >> 3;                          // 0..7
  int srcSlot   = (lane & 7) ^ rowInWave;             // pre-swizzled 16B slot

  f32x4 acc[4][4] = {};

  for (int kk = 0; kk < 4; ++kk) {
#pragma unroll
    for (int i = 0; i < 4; ++i) {
      int rl = i * 32 + w * 8 + rowInWave;
      int rgA = m0 + rl;
      if (rgA > M_ - 1) rgA = M_ - 1;                 // clamp pad rows
      gload_lds16(A + (size_t)rgA * 256 + kk * 64 + srcSlot * 8,
                  lA + (i * 32 + w * 8) * 64);
      int rgB = n0 + rl;                              // 768 % 128 == 0
      gload_lds16(Wf + (size_t)rgB * 256 + kk * 64 + srcSlot * 8,
                  lB + (i * 32 + w * 8) * 64);
    }
    __syncthreads();

    const char* baseA = (const char*)lA;
    const char* baseB = (const char*)lB;
#pragma unroll
    for (int ki = 0; ki < 2; ++ki) {
      bf16x8 af[4], bfr[4];
#pragma unroll
      for (int mi = 0; mi < 4; ++mi) {
        int r  = wr * 64 + mi * 16 + (lane & 15);
        int cb = ki * 64 + (lane >> 4) * 16;          // byte offset in row
        af[mi] = *(const bf16x8*)(baseA + r * 128 + (cb ^ ((r & 7) << 4)));
      }
#pragma unroll
      for (int ni = 0; ni < 4; ++ni) {
        int r  = wc * 64 + ni * 16 + (lane & 15);
        int cb = ki * 64 + (lane >> 4) * 16;
        bfr[ni] = *(const bf16x8*)(baseB + r * 128 + (cb ^ ((r & 7) << 4)));
      }
#pragma unroll
      for (int mi = 0; mi < 4; ++mi)
#pragma unroll
        for (int ni = 0; ni < 4; ++ni)
          acc[mi][ni] = __builtin_amdgcn_mfma_f32_16x16x32_bf16(
              af[mi], bfr[ni], acc[mi][ni], 0, 0, 0);
    }
    __syncthreads();
  }

  // epilogue: C/D layout col = lane&15, row = (lane>>4)*4 + reg
#pragma unroll
  for (int ni = 0; ni < 4; ++ni) {
    int col = n0 + wc * 64 + ni * 16 + (lane & 15);   // 0..767
    float bias = (col < 256) ? bq[col] : (col < 512) ? bk[col - 256] : bv[col - 512];
#pragma unroll
    for (int mi = 0; mi < 4; ++mi) {
      int rowb = m0 + wr * 64 + mi * 16 + ((lane >> 4) * 4);
#pragma unroll
      for (int r = 0; r < 4; ++r) {
        int row = rowb + r;
        if (row < M_)
          C[(size_t)row * 768 + col] = f2bf(acc[mi][ni][r] + bias);
      }
    }
  }
}

// ---------------------------------------------------------------------------
// K3: windowed attention + exp_map0. One wave per (bj, t).
// qkv: bf16 [MPAD_][768] (q | k | v). out: fp32 [B][T][J][257]
// ---------------------------------------------------------------------------
__global__ __launch_bounds__(256) void attn_kernel(
    const unsigned short* __restrict__ qkv, const float* __restrict__ tau,
    float* __restrict__ out) {
  int wid  = threadIdx.x >> 6;
  int lane = threadIdx.x & 63;
  int t = blockIdx.x * 4 + wid;
  if (t >= T_) return;
  int bj = blockIdx.y;
  int b = bj / J_, j = bj % J_;
  size_t mrow = (size_t)bj * T_ + t;

  float tauc = fmaxf(tau[0], 1e-3f);
  float sc = 1.f / (16.f * tauc);                     // sqrt(256) = 16

  float q[4];
  {
    ushort4 qa = *(const ushort4*)(qkv + mrow * 768 + lane * 4);
    q[0] = bf2f(qa.x); q[1] = bf2f(qa.y); q[2] = bf2f(qa.z); q[3] = bf2f(qa.w);
  }

  float logit[7];
#pragma unroll
  for (int ww = 0; ww < 7; ++ww) {
    int t2 = t + ww - 3;
    float d = -INFINITY;
    if (t2 >= 0 && t2 < T_) {                         // wave-uniform branch
      size_t m2 = (size_t)bj * T_ + t2;
      ushort4 ka = *(const ushort4*)(qkv + m2 * 768 + 256 + lane * 4);
      float p = q[0] * bf2f(ka.x) + q[1] * bf2f(ka.y) +
                q[2] * bf2f(ka.z) + q[3] * bf2f(ka.w);
      d = wave_sum(p) * sc;
    }
    logit[ww] = d;
  }

  float mx = logit[0];
#pragma unroll
  for (int ww = 1; ww < 7; ++ww) mx = fmaxf(mx, logit[ww]);
  float e[7], s = 0.f;
#pragma unroll
  for (int ww = 0; ww < 7; ++ww) {
    e[ww] = expf(logit[ww] - mx);                     // exp(-inf) = 0
    s += e[ww];
  }
  float inv = 1.f / s;

  float agg[4] = {0.f, 0.f, 0.f, 0.f};
#pragma unroll
  for (int ww = 0; ww < 7; ++ww) {
    int t2 = t + ww - 3;
    if (t2 >= 0 && t2 < T_) {
      size_t m2 = (size_t)bj * T_ + t2;
      ushort4 va = *(const ushort4*)(qkv + m2 * 768 + 512 + lane * 4);
      agg[0] += e[ww] * bf2f(va.x);
      agg[1] += e[ww] * bf2f(va.y);
      agg[2] += e[ww] * bf2f(va.z);
      agg[3] += e[ww] * bf2f(va.w);
    }
  }
#pragma unroll
  for (int i = 0; i < 4; ++i) agg[i] *= inv;

  float nn = agg[0]*agg[0] + agg[1]*agg[1] + agg[2]*agg[2] + agg[3]*agg[3];
  nn = wave_sum(nn);
  float n = fmaxf(sqrtf(nn), 1e-7f);
  float scale = sinhf(n) / n;

  float* orow = out + ((size_t)(b * T_ + t) * J_ + j) * D_;
  if (lane == 0) orow[0] = coshf(n);
#pragma unroll
  for (int i = 0; i < 4; ++i) orow[1 + lane * 4 + i] = agg[i] * scale;
}

// ---------------------------------------------------------------------------
extern "C" void kernel_launch(void* const* d_in, const int* in_sizes, int n_in,
                              void* d_out, int out_size, void* d_ws, size_t ws_size,
                              hipStream_t stream) {
  const float* x   = (const float*)d_in[0];
  // d_in[1] = vel_seq: unused by the reference
  const float* tau = (const float*)d_in[2];
  const float* Wq  = (const float*)d_in[3];
  const float* bq  = (const float*)d_in[4];
  const float* Wk  = (const float*)d_in[5];
  const float* bk  = (const float*)d_in[6];
  const float* Wv  = (const float*)d_in[7];
  const float* bv  = (const float*)d_in[8];
  float* out = (float*)d_out;

  char* ws = (char*)d_ws;
  // ws layout: wf 393216 B | spatial MPAD_*256*2 B | qkv MPAD_*768*2 B  (~136 MB)
  __hip_bfloat16* wf  = (__hip_bfloat16*)(ws);
  unsigned short* sp  = (unsigned short*)(ws + 393216);
  unsigned short* qkv = (unsigned short*)(ws + 393216 + (size_t)MPAD_ * 256 * 2);

  fuse_w_kernel<<<dim3(768), dim3(256), 0, stream>>>(Wq, Wk, Wv, wf);
  spatial_kernel<<<dim3(61, BJ_), dim3(256), 0, stream>>>(x, sp);
  qkv_gemm_kernel<<<dim3(517, 6), dim3(256), 0, stream>>>(
      sp, (const unsigned short*)wf, bq, bk, bv, qkv);
  attn_kernel<<<dim3(61, BJ_), dim3(256), 0, stream>>>(qkv, tau, out);
}

// Round 2
// 343.327 us; speedup vs baseline: 1.0337x; 1.0337x over previous
//
#include <hip/hip_runtime.h>
#include <hip/hip_bf16.h>

#define B_   16
#define T_   243
#define J_   17
#define E_   256
#define D_   257
#define BJ_  (B_ * J_)      // 272
#define M_   (BJ_ * T_)     // 66096

typedef __bf16 bf16x8 __attribute__((ext_vector_type(8)));
typedef float  f32x4  __attribute__((ext_vector_type(4)));

static __device__ __forceinline__ float bf2f(unsigned short u) {
  unsigned int v = ((unsigned int)u) << 16;
  return __builtin_bit_cast(float, v);
}
static __device__ __forceinline__ unsigned short f2bf(float f) {
  __hip_bfloat16 h = __float2bfloat16(f);
  return __builtin_bit_cast(unsigned short, h);
}
static __device__ __forceinline__ float wave_sum(float v) {
  v += __shfl_xor(v, 1);
  v += __shfl_xor(v, 2);
  v += __shfl_xor(v, 4);
  v += __shfl_xor(v, 8);
  v += __shfl_xor(v, 16);
  v += __shfl_xor(v, 32);
  return v;
}
static __device__ __forceinline__ void gload_lds16(const void* g, void* l) {
  __builtin_amdgcn_global_load_lds(
      (const __attribute__((address_space(1))) void*)g,
      (__attribute__((address_space(3))) void*)l, 16, 0, 0);
}

// ---------------------------------------------------------------------------
// K0: fuse Wq/Wk/Wv (fp32, [256][256] row-major, n-major) -> bf16 [768][256]
// ---------------------------------------------------------------------------
__global__ void fuse_w_kernel(const float* __restrict__ Wq,
                              const float* __restrict__ Wk,
                              const float* __restrict__ Wv,
                              __hip_bfloat16* __restrict__ wf) {
  int idx = blockIdx.x * 256 + threadIdx.x;  // 0 .. 196607
  float v = (idx < 65536) ? Wq[idx]
          : (idx < 131072) ? Wk[idx - 65536]
                           : Wv[idx - 131072];
  ((unsigned short*)wf)[idx] = f2bf(v);
}

// ---------------------------------------------------------------------------
// K1: fused spatial + QKV GEMM.
// Block = 512 threads (8 waves), one 128-row m-tile, n-loop over 6 tiles of 128.
// Phase 1: compute spatial(x) for 128 rows -> lA (bf16 [128][256], XOR-swizzled).
// Phase 2: per n-tile: stream Wf chunks (BK=64, double-buffered global_load_lds
//          with pre-swizzled source), MFMA, LDS-staged coalesced C store.
// Wave grid 2(m) x 4(n): wave tile 64 rows x 32 cols -> acc[4][2] f32x4.
// ---------------------------------------------------------------------------
__global__ __launch_bounds__(512) void qkv_fused_kernel(
    const float* __restrict__ x, const unsigned short* __restrict__ Wf,
    const float* __restrict__ bq, const float* __restrict__ bk,
    const float* __restrict__ bv, unsigned short* __restrict__ C) {
  __shared__ __align__(16) unsigned short lA[128 * 256];   // 64 KB
  __shared__ __align__(16) unsigned short lW[2][128 * 64]; // 32 KB (also C stage)

  int tid  = threadIdx.x;
  int w    = tid >> 6;          // 0..7
  int lane = tid & 63;
  int wr   = w >> 2;            // 0..1 : 64-row half
  int wcn  = w & 3;             // 0..3 : 32-col quarter
  int m0   = blockIdx.x * 128;

  // ---- Phase 1: spatial -> lA (swizzled) --------------------------------
  {
    char* bA = (char*)lA;
    for (int rr = 0; rr < 16; ++rr) {
      int lr = w * 16 + rr;
      int m  = m0 + lr; if (m > M_ - 1) m = M_ - 1;
      int bj = m / T_;  int t = m - bj * T_;
      int b  = bj / J_; int j = bj - b * J_;
      const float* row = x + (size_t)((b * T_ + t) * J_ + j) * D_;
      float xs[4], ss = 0.f;
#pragma unroll
      for (int i = 0; i < 4; ++i) {
        xs[i] = row[1 + lane * 4 + i];
        ss += xs[i] * xs[i];
      }
      ss = wave_sum(ss);
      float xn = fmaxf(sqrtf(ss), 1e-7f);
      float alpha = acoshf(fmaxf(row[0], 1.f + 1e-7f)) / xn;
      ushort4 o;
      o.x = f2bf(xs[0] * alpha); o.y = f2bf(xs[1] * alpha);
      o.z = f2bf(xs[2] * alpha); o.w = f2bf(xs[3] * alpha);
      int byte = lr * 512 + ((lane * 8) ^ ((lr & 7) << 4));
      *(ushort4*)(bA + byte) = o;
    }
  }
  __syncthreads();

  // staging geometry (same proven pattern as round 1: 0 bank conflicts)
  int rowInWave = lane >> 3;                 // 0..7
  int srcSlot   = (lane & 7) ^ rowInWave;    // pre-swizzled 16B slot

  const char* bA = (const char*)lA;

  for (int nt = 0; nt < 6; ++nt) {
    int n0 = nt * 128;

    // bias for this wave's two 16-col fragments (uniform q/k/v region per tile)
    float bias[2];
#pragma unroll
    for (int ni = 0; ni < 2; ++ni) {
      int colg = n0 + wcn * 32 + ni * 16 + (lane & 15);
      bias[ni] = (colg < 256) ? bq[colg]
               : (colg < 512) ? bk[colg - 256] : bv[colg - 512];
    }

    f32x4 acc[4][2] = {};

    // stage kk=0 into buf0
#pragma unroll
    for (int i = 0; i < 2; ++i) {
      int rbase = (w * 2 + i) * 8;
      gload_lds16(Wf + (size_t)(n0 + rbase + rowInWave) * 256 + srcSlot * 8,
                  lW[0] + rbase * 64);
    }
    __syncthreads();

    for (int kk = 0; kk < 4; ++kk) {
      if (kk < 3) {
#pragma unroll
        for (int i = 0; i < 2; ++i) {
          int rbase = (w * 2 + i) * 8;
          gload_lds16(Wf + (size_t)(n0 + rbase + rowInWave) * 256 +
                          (kk + 1) * 64 + srcSlot * 8,
                      lW[(kk + 1) & 1] + rbase * 64);
        }
      }
      const char* bW = (const char*)lW[kk & 1];
#pragma unroll
      for (int ki = 0; ki < 2; ++ki) {
        bf16x8 a[4], bfr[2];
        int cbA = kk * 128 + ki * 64 + (lane >> 4) * 16;
#pragma unroll
        for (int mi = 0; mi < 4; ++mi) {
          int r = wr * 64 + mi * 16 + (lane & 15);
          a[mi] = *(const bf16x8*)(bA + r * 512 + (cbA ^ ((r & 7) << 4)));
        }
        int cbB = ki * 64 + (lane >> 4) * 16;
#pragma unroll
        for (int ni = 0; ni < 2; ++ni) {
          int r = wcn * 32 + ni * 16 + (lane & 15);
          bfr[ni] = *(const bf16x8*)(bW + r * 128 + (cbB ^ ((r & 7) << 4)));
        }
#pragma unroll
        for (int mi = 0; mi < 4; ++mi)
#pragma unroll
          for (int ni = 0; ni < 2; ++ni)
            acc[mi][ni] = __builtin_amdgcn_mfma_f32_16x16x32_bf16(
                a[mi], bfr[ni], acc[mi][ni], 0, 0, 0);
      }
      __syncthreads();
    }

    // ---- epilogue: acc -> swizzled LDS tile -> coalesced global ---------
    char* bC = (char*)lW[0];  // 32 KB = [128][128] bf16 (swizzled rows)
#pragma unroll
    for (int mi = 0; mi < 4; ++mi)
#pragma unroll
      for (int ni = 0; ni < 2; ++ni) {
        int col = wcn * 32 + ni * 16 + (lane & 15);
#pragma unroll
        for (int r = 0; r < 4; ++r) {
          int row  = wr * 64 + mi * 16 + (lane >> 4) * 4 + r;
          int byte = row * 256 + ((col * 2) ^ ((row & 7) << 4));
          *(unsigned short*)(bC + byte) = f2bf(acc[mi][ni][r] + bias[ni]);
        }
      }
    __syncthreads();
#pragma unroll
    for (int p = 0; p < 4; ++p) {
      int row  = p * 32 + (tid >> 4);
      int seg  = tid & 15;
      int byte = row * 256 + ((seg * 16) ^ ((row & 7) << 4));
      uint4 val = *(const uint4*)(bC + byte);
      int gm = m0 + row;
      if (gm < M_)
        *(uint4*)(C + (size_t)gm * 768 + n0 + seg * 8) = val;
    }
    __syncthreads();
  }
}

// ---------------------------------------------------------------------------
// K2: windowed attention + exp_map0. One wave per (bj, t).
// qkv: bf16 [M_][768] (q | k | v). out: fp32 [B][T][J][257]
// ---------------------------------------------------------------------------
__global__ __launch_bounds__(256) void attn_kernel(
    const unsigned short* __restrict__ qkv, const float* __restrict__ tau,
    float* __restrict__ out) {
  int wid  = threadIdx.x >> 6;
  int lane = threadIdx.x & 63;
  int t = blockIdx.x * 4 + wid;
  if (t >= T_) return;
  int bj = blockIdx.y;
  int b = bj / J_, j = bj % J_;
  size_t mrow = (size_t)bj * T_ + t;

  float tauc = fmaxf(tau[0], 1e-3f);
  float sc = 1.f / (16.f * tauc);                     // sqrt(256) = 16

  float q[4];
  {
    ushort4 qa = *(const ushort4*)(qkv + mrow * 768 + lane * 4);
    q[0] = bf2f(qa.x); q[1] = bf2f(qa.y); q[2] = bf2f(qa.z); q[3] = bf2f(qa.w);
  }

  float logit[7];
#pragma unroll
  for (int ww = 0; ww < 7; ++ww) {
    int t2 = t + ww - 3;
    float d = -INFINITY;
    if (t2 >= 0 && t2 < T_) {                         // wave-uniform branch
      size_t m2 = (size_t)bj * T_ + t2;
      ushort4 ka = *(const ushort4*)(qkv + m2 * 768 + 256 + lane * 4);
      float p = q[0] * bf2f(ka.x) + q[1] * bf2f(ka.y) +
                q[2] * bf2f(ka.z) + q[3] * bf2f(ka.w);
      d = wave_sum(p) * sc;
    }
    logit[ww] = d;
  }

  float mx = logit[0];
#pragma unroll
  for (int ww = 1; ww < 7; ++ww) mx = fmaxf(mx, logit[ww]);
  float e[7], s = 0.f;
#pragma unroll
  for (int ww = 0; ww < 7; ++ww) {
    e[ww] = expf(logit[ww] - mx);                     // exp(-inf) = 0
    s += e[ww];
  }
  float inv = 1.f / s;

  float agg[4] = {0.f, 0.f, 0.f, 0.f};
#pragma unroll
  for (int ww = 0; ww < 7; ++ww) {
    int t2 = t + ww - 3;
    if (t2 >= 0 && t2 < T_) {
      size_t m2 = (size_t)bj * T_ + t2;
      ushort4 va = *(const ushort4*)(qkv + m2 * 768 + 512 + lane * 4);
      agg[0] += e[ww] * bf2f(va.x);
      agg[1] += e[ww] * bf2f(va.y);
      agg[2] += e[ww] * bf2f(va.z);
      agg[3] += e[ww] * bf2f(va.w);
    }
  }
#pragma unroll
  for (int i = 0; i < 4; ++i) agg[i] *= inv;

  float nn = agg[0]*agg[0] + agg[1]*agg[1] + agg[2]*agg[2] + agg[3]*agg[3];
  nn = wave_sum(nn);
  float n = fmaxf(sqrtf(nn), 1e-7f);
  float scale = sinhf(n) / n;

  float* orow = out + ((size_t)(b * T_ + t) * J_ + j) * D_;
  if (lane == 0) orow[0] = coshf(n);
#pragma unroll
  for (int i = 0; i < 4; ++i) orow[1 + lane * 4 + i] = agg[i] * scale;
}

// ---------------------------------------------------------------------------
extern "C" void kernel_launch(void* const* d_in, const int* in_sizes, int n_in,
                              void* d_out, int out_size, void* d_ws, size_t ws_size,
                              hipStream_t stream) {
  const float* x   = (const float*)d_in[0];
  // d_in[1] = vel_seq: unused by the reference
  const float* tau = (const float*)d_in[2];
  const float* Wq  = (const float*)d_in[3];
  const float* bq  = (const float*)d_in[4];
  const float* Wk  = (const float*)d_in[5];
  const float* bk  = (const float*)d_in[6];
  const float* Wv  = (const float*)d_in[7];
  const float* bv  = (const float*)d_in[8];
  float* out = (float*)d_out;

  char* ws = (char*)d_ws;
  // ws layout: wf 393216 B | qkv M_*768*2 B  (~102 MB total)
  __hip_bfloat16* wf  = (__hip_bfloat16*)(ws);
  unsigned short* qkv = (unsigned short*)(ws + 393216);

  fuse_w_kernel<<<dim3(768), dim3(256), 0, stream>>>(Wq, Wk, Wv, wf);
  qkv_fused_kernel<<<dim3(517), dim3(512), 0, stream>>>(
      x, (const unsigned short*)wf, bq, bk, bv, qkv);
  attn_kernel<<<dim3(61, BJ_), dim3(256), 0, stream>>>(qkv, tau, out);
}

// Round 3
// 321.618 us; speedup vs baseline: 1.1034x; 1.0675x over previous
//
#include <hip/hip_runtime.h>
#include <hip/hip_bf16.h>

#define B_   16
#define T_   243
#define J_   17
#define E_   256
#define D_   257
#define BJ_  (B_ * J_)      // 272
#define M_   (BJ_ * T_)     // 66096

typedef __bf16 bf16x8 __attribute__((ext_vector_type(8)));
typedef float  f32x4  __attribute__((ext_vector_type(4)));

static __device__ __forceinline__ float bf2f(unsigned short u) {
  unsigned int v = ((unsigned int)u) << 16;
  return __builtin_bit_cast(float, v);
}
static __device__ __forceinline__ unsigned short f2bf(float f) {
  __hip_bfloat16 h = __float2bfloat16(f);
  return __builtin_bit_cast(unsigned short, h);
}
static __device__ __forceinline__ float wave_sum(float v) {
  v += __shfl_xor(v, 1);
  v += __shfl_xor(v, 2);
  v += __shfl_xor(v, 4);
  v += __shfl_xor(v, 8);
  v += __shfl_xor(v, 16);
  v += __shfl_xor(v, 32);
  return v;
}
static __device__ __forceinline__ void gload_lds16(const void* g, void* l) {
  __builtin_amdgcn_global_load_lds(
      (const __attribute__((address_space(1))) void*)g,
      (__attribute__((address_space(3))) void*)l, 16, 0, 0);
}

// ---------------------------------------------------------------------------
// K0: fuse Wq/Wk/Wv (fp32, [256][256] row-major, n-major) -> bf16 [768][256]
// ---------------------------------------------------------------------------
__global__ void fuse_w_kernel(const float* __restrict__ Wq,
                              const float* __restrict__ Wk,
                              const float* __restrict__ Wv,
                              __hip_bfloat16* __restrict__ wf) {
  int idx = blockIdx.x * 256 + threadIdx.x;  // 0 .. 196607
  float v = (idx < 65536) ? Wq[idx]
          : (idx < 131072) ? Wk[idx - 65536]
                           : Wv[idx - 131072];
  ((unsigned short*)wf)[idx] = f2bf(v);
}

// ---------------------------------------------------------------------------
// K1: fused spatial + QKV GEMM.
// Block = 256 threads (4 waves), one 64-row m-tile, n-loop over 6 tiles of 128.
// LDS 64 KB total -> 2 blocks/CU (round-2 lesson: 96 KB -> 1 block/CU killed it).
// Phase 1: spatial(x) for 64 rows -> lA (bf16 [64][256], XOR-swizzled).
// Phase 2: per n-tile: stream Wf (BK=64, dbuf global_load_lds w/ pre-swizzled
//          source), MFMA, LDS-staged coalesced C store (reuses lW[0]).
// Wave grid 2(m) x 2(n): wave tile 32 rows x 64 cols -> acc[2][4] f32x4.
// ---------------------------------------------------------------------------
__global__ __launch_bounds__(256) void qkv_gemm_kernel(
    const float* __restrict__ x, const unsigned short* __restrict__ Wf,
    const float* __restrict__ bq, const float* __restrict__ bk,
    const float* __restrict__ bv, unsigned short* __restrict__ C) {
  __shared__ __align__(16) unsigned short lA[64 * 256];    // 32 KB
  __shared__ __align__(16) unsigned short lW[2][128 * 64]; // 2x16 KB (lW[0] = C stage)

  int tid  = threadIdx.x;
  int w    = tid >> 6;          // 0..3
  int lane = tid & 63;
  int wr   = w >> 1;            // 0..1 : 32-row half
  int wcn  = w & 1;             // 0..1 : 64-col half
  int m0   = blockIdx.x * 64;

  // ---- Phase 1: spatial -> lA (swizzled) --------------------------------
  {
    char* bA = (char*)lA;
    for (int rr = 0; rr < 16; ++rr) {
      int lr = w * 16 + rr;
      int m  = m0 + lr; if (m > M_ - 1) m = M_ - 1;
      int bj = m / T_;  int t = m - bj * T_;
      int b  = bj / J_; int j = bj - b * J_;
      const float* row = x + (size_t)((b * T_ + t) * J_ + j) * D_;
      float xs[4], ss = 0.f;
#pragma unroll
      for (int i = 0; i < 4; ++i) {
        xs[i] = row[1 + lane * 4 + i];
        ss += xs[i] * xs[i];
      }
      ss = wave_sum(ss);
      float xn = fmaxf(sqrtf(ss), 1e-7f);
      float alpha = acoshf(fmaxf(row[0], 1.f + 1e-7f)) / xn;
      ushort4 o;
      o.x = f2bf(xs[0] * alpha); o.y = f2bf(xs[1] * alpha);
      o.z = f2bf(xs[2] * alpha); o.w = f2bf(xs[3] * alpha);
      int byte = lr * 512 + ((lane * 8) ^ ((lr & 7) << 4));
      *(ushort4*)(bA + byte) = o;
    }
  }
  __syncthreads();

  // staging geometry (proven: 0 bank conflicts on the global_load_lds path)
  int rowInWave = lane >> 3;                 // 0..7
  int srcSlot   = (lane & 7) ^ rowInWave;    // pre-swizzled 16B slot

  const char* bA = (const char*)lA;

  for (int nt = 0; nt < 6; ++nt) {
    int n0 = nt * 128;

    float bias[4];
#pragma unroll
    for (int ni = 0; ni < 4; ++ni) {
      int colg = n0 + wcn * 64 + ni * 16 + (lane & 15);
      bias[ni] = (colg < 256) ? bq[colg]
               : (colg < 512) ? bk[colg - 256] : bv[colg - 512];
    }

    f32x4 acc[2][4] = {};

    // stage kk=0 into buf0: 128(n) x 64(k) bf16, 4 issues/wave
#pragma unroll
    for (int i = 0; i < 4; ++i) {
      int rbase = (w * 4 + i) * 8;
      gload_lds16(Wf + (size_t)(n0 + rbase + rowInWave) * 256 + srcSlot * 8,
                  lW[0] + rbase * 64);
    }
    __syncthreads();

    for (int kk = 0; kk < 4; ++kk) {
      if (kk < 3) {
#pragma unroll
        for (int i = 0; i < 4; ++i) {
          int rbase = (w * 4 + i) * 8;
          gload_lds16(Wf + (size_t)(n0 + rbase + rowInWave) * 256 +
                          (kk + 1) * 64 + srcSlot * 8,
                      lW[(kk + 1) & 1] + rbase * 64);
        }
      }
      const char* bW = (const char*)lW[kk & 1];
#pragma unroll
      for (int ki = 0; ki < 2; ++ki) {
        bf16x8 a[2], bfr[4];
        int cbA = kk * 128 + ki * 64 + (lane >> 4) * 16;
#pragma unroll
        for (int mi = 0; mi < 2; ++mi) {
          int r = wr * 32 + mi * 16 + (lane & 15);
          a[mi] = *(const bf16x8*)(bA + r * 512 + (cbA ^ ((r & 7) << 4)));
        }
        int cbB = ki * 64 + (lane >> 4) * 16;
#pragma unroll
        for (int ni = 0; ni < 4; ++ni) {
          int r = wcn * 64 + ni * 16 + (lane & 15);
          bfr[ni] = *(const bf16x8*)(bW + r * 128 + (cbB ^ ((r & 7) << 4)));
        }
#pragma unroll
        for (int mi = 0; mi < 2; ++mi)
#pragma unroll
          for (int ni = 0; ni < 4; ++ni)
            acc[mi][ni] = __builtin_amdgcn_mfma_f32_16x16x32_bf16(
                a[mi], bfr[ni], acc[mi][ni], 0, 0, 0);
      }
      __syncthreads();
    }

    // ---- epilogue: acc -> swizzled LDS tile -> coalesced global ---------
    char* bC = (char*)lW[0];  // 16 KB = [64][128] bf16 (swizzled rows)
#pragma unroll
    for (int mi = 0; mi < 2; ++mi)
#pragma unroll
      for (int ni = 0; ni < 4; ++ni) {
        int col = wcn * 64 + ni * 16 + (lane & 15);
#pragma unroll
        for (int r = 0; r < 4; ++r) {
          int row  = wr * 32 + mi * 16 + (lane >> 4) * 4 + r;
          int byte = row * 256 + ((col * 2) ^ ((row & 7) << 4));
          *(unsigned short*)(bC + byte) = f2bf(acc[mi][ni][r] + bias[ni]);
        }
      }
    __syncthreads();
#pragma unroll
    for (int p = 0; p < 4; ++p) {
      int row  = p * 16 + (tid >> 4);
      int seg  = tid & 15;
      int byte = row * 256 + ((seg * 16) ^ ((row & 7) << 4));
      uint4 val = *(const uint4*)(bC + byte);
      int gm = m0 + row;
      if (gm < M_)
        *(uint4*)(C + (size_t)gm * 768 + n0 + seg * 8) = val;
    }
    __syncthreads();
  }
}

// ---------------------------------------------------------------------------
// K2: windowed attention + exp_map0. One wave per (bj, 16-frame t-chunk).
// All 15 row loads (q, 7k, 7v) issued up-front per t for ILP; boundary
// neighbors use clamped addresses + -inf logit mask. No LDS, no barriers.
// qkv: bf16 [M_][768] (q | k | v). out: fp32 [B][T][J][257]
// ---------------------------------------------------------------------------
__global__ __launch_bounds__(256) void attn_kernel(
    const unsigned short* __restrict__ qkv, const float* __restrict__ tau,
    float* __restrict__ out) {
  int wid  = threadIdx.x >> 6;
  int lane = threadIdx.x & 63;
  int c  = blockIdx.x * 4 + wid;          // chunk 0..15
  int t0 = c * 16;
  int t1 = min(T_, t0 + 16);
  int bj = blockIdx.y;
  int b = bj / J_, j = bj % J_;
  const unsigned short* base = qkv + (size_t)bj * T_ * 768;

  float tauc = fmaxf(tau[0], 1e-3f);
  float sc = 1.f / (16.f * tauc);         // sqrt(256) = 16

  for (int t = t0; t < t1; ++t) {
    // issue all 15 row loads up-front (independent -> one latency exposure)
    ushort4 qa = *(const ushort4*)(base + (size_t)t * 768 + lane * 4);
    ushort4 ka[7], va[7];
#pragma unroll
    for (int ww = 0; ww < 7; ++ww) {
      int t2 = t + ww - 3;
      int tc = min(max(t2, 0), T_ - 1);
      const unsigned short* rowp = base + (size_t)tc * 768;
      ka[ww] = *(const ushort4*)(rowp + 256 + lane * 4);
      va[ww] = *(const ushort4*)(rowp + 512 + lane * 4);
    }
    float q0 = bf2f(qa.x), q1 = bf2f(qa.y), q2 = bf2f(qa.z), q3 = bf2f(qa.w);

    float logit[7];
#pragma unroll
    for (int ww = 0; ww < 7; ++ww) {
      float p = q0 * bf2f(ka[ww].x) + q1 * bf2f(ka[ww].y) +
                q2 * bf2f(ka[ww].z) + q3 * bf2f(ka[ww].w);
      p = wave_sum(p) * sc;
      int t2 = t + ww - 3;
      logit[ww] = (t2 < 0 || t2 >= T_) ? -INFINITY : p;
    }

    float mx = logit[0];
#pragma unroll
    for (int ww = 1; ww < 7; ++ww) mx = fmaxf(mx, logit[ww]);
    float e[7], s = 0.f;
#pragma unroll
    for (int ww = 0; ww < 7; ++ww) {
      e[ww] = expf(logit[ww] - mx);       // exp(-inf) = 0 masks boundary
      s += e[ww];
    }
    float inv = 1.f / s;

    float ag0 = 0.f, ag1 = 0.f, ag2 = 0.f, ag3 = 0.f;
#pragma unroll
    for (int ww = 0; ww < 7; ++ww) {
      ag0 += e[ww] * bf2f(va[ww].x);
      ag1 += e[ww] * bf2f(va[ww].y);
      ag2 += e[ww] * bf2f(va[ww].z);
      ag3 += e[ww] * bf2f(va[ww].w);
    }
    ag0 *= inv; ag1 *= inv; ag2 *= inv; ag3 *= inv;

    float nn = wave_sum(ag0*ag0 + ag1*ag1 + ag2*ag2 + ag3*ag3);
    float n = fmaxf(sqrtf(nn), 1e-7f);
    float scale = sinhf(n) / n;

    float* orow = out + ((size_t)(b * T_ + t) * J_ + j) * D_;
    if (lane == 0) orow[0] = coshf(n);
    float4 o; o.x = ag0 * scale; o.y = ag1 * scale;
    o.z = ag2 * scale; o.w = ag3 * scale;
    *(float4*)(orow + 1 + lane * 4) = o;
  }
}

// ---------------------------------------------------------------------------
extern "C" void kernel_launch(void* const* d_in, const int* in_sizes, int n_in,
                              void* d_out, int out_size, void* d_ws, size_t ws_size,
                              hipStream_t stream) {
  const float* x   = (const float*)d_in[0];
  // d_in[1] = vel_seq: unused by the reference
  const float* tau = (const float*)d_in[2];
  const float* Wq  = (const float*)d_in[3];
  const float* bq  = (const float*)d_in[4];
  const float* Wk  = (const float*)d_in[5];
  const float* bk  = (const float*)d_in[6];
  const float* Wv  = (const float*)d_in[7];
  const float* bv  = (const float*)d_in[8];
  float* out = (float*)d_out;

  char* ws = (char*)d_ws;
  // ws layout: wf 393216 B | qkv M_*768*2 B  (~102 MB total)
  __hip_bfloat16* wf  = (__hip_bfloat16*)(ws);
  unsigned short* qkv = (unsigned short*)(ws + 393216);

  fuse_w_kernel<<<dim3(768), dim3(256), 0, stream>>>(Wq, Wk, Wv, wf);
  qkv_gemm_kernel<<<dim3(1034), dim3(256), 0, stream>>>(
      x, (const unsigned short*)wf, bq, bk, bv, qkv);
  attn_kernel<<<dim3(4, BJ_), dim3(256), 0, stream>>>(qkv, tau, out);
}